// Round 7
// baseline (463.353 us; speedup 1.0000x reference)
//
#include <hip/hip_runtime.h>
#include <hip/hip_bf16.h>

// B=16, N=512, D=512, H=8, HD=64, K(topk)=16, MSL=512
#define BB 16
#define NN 512
#define DD 512
#define HH 8
#define HD 64
#define MM (BB*NN)      // 8192 rows
#define DFF 2048

typedef __attribute__((ext_vector_type(8))) short bf16x8;
typedef __attribute__((ext_vector_type(4))) float fx4;

static __device__ __forceinline__ unsigned short f2bf(float f) {
  unsigned u = __float_as_uint(f);
  u += 0x7FFFu + ((u >> 16) & 1u);   // RNE
  return (unsigned short)(u >> 16);
}
static __device__ __forceinline__ float bf2f(unsigned short s) {
  return __uint_as_float(((unsigned)s) << 16);
}

// async global->LDS DMA, 16B/lane, dest = wave-uniform base + lane*16
static __device__ __forceinline__ void load_lds16(const unsigned short* g, unsigned short* l) {
  __builtin_amdgcn_global_load_lds(
      (const __attribute__((address_space(1))) void*)g,
      (__attribute__((address_space(3))) void*)l, 16, 0, 0);
}

// ---------------- fused weight transpose: 6 matrices [K][N] fp32 -> [N][K] bf16 ----------------
__global__ void transpose_all(const float* __restrict__ wq, const float* __restrict__ wk,
                              const float* __restrict__ wv, const float* __restrict__ wo,
                              const float* __restrict__ w1, const float* __restrict__ w2,
                              unsigned short* __restrict__ wqkvT, unsigned short* __restrict__ woT,
                              unsigned short* __restrict__ w1T, unsigned short* __restrict__ w2T) {
  __shared__ float tl[32][33];
  int id = blockIdx.x;
  const float* src; unsigned short* dst; int K, N, bx, by;
  if (id < 1024) {
    int m = id >> 8, tt = id & 255;
    src = (m == 0) ? wq : (m == 1) ? wk : (m == 2) ? wv : wo;
    dst = (m == 3) ? woT : wqkvT + m * 512 * 512;
    K = 512; N = 512; bx = tt & 15; by = tt >> 4;
  } else if (id < 2048) {
    int tt = id - 1024;
    src = w1; dst = w1T; K = 512; N = 2048; bx = tt & 63; by = tt >> 6;
  } else {
    int tt = id - 2048;
    src = w2; dst = w2T; K = 2048; N = 512; bx = tt & 15; by = tt >> 4;
  }
  int tx = threadIdx.x, ty = threadIdx.y;        // (32,8)
  int x0 = bx * 32, y0 = by * 32;
  #pragma unroll
  for (int i = 0; i < 4; i++)
    tl[ty + i*8][tx] = src[(size_t)(y0 + ty + i*8) * N + x0 + tx];
  __syncthreads();
  #pragma unroll
  for (int i = 0; i < 4; i++)
    dst[(size_t)(x0 + ty + i*8) * K + y0 + tx] = f2bf(tl[tx][ty + i*8]);
}

__global__ void concat_bias(const float* __restrict__ bq, const float* __restrict__ bk,
                            const float* __restrict__ bv, float* __restrict__ o) {
  int t = blockIdx.x * 256 + threadIdx.x;
  if (t < 512) o[t] = bq[t];
  else if (t < 1024) o[t] = bk[t - 512];
  else if (t < 1536) o[t] = bv[t - 1024];
}

// ---------------- LayerNorm: fp32 [rows][512] -> bf16 ----------------
__global__ __launch_bounds__(256) void ln_kernel(const float* __restrict__ X,
                                                 const float* __restrict__ g,
                                                 const float* __restrict__ be,
                                                 unsigned short* __restrict__ O) {
  int w = threadIdx.x >> 6, l = threadIdx.x & 63;
  size_t row = (size_t)blockIdx.x * 4 + w;
  const float* xr = X + row * 512;
  fx4 a = *(const fx4*)(xr + l*4);
  fx4 c = *(const fx4*)(xr + 256 + l*4);
  float s = a[0]+a[1]+a[2]+a[3] + c[0]+c[1]+c[2]+c[3];
  float q = a[0]*a[0]+a[1]*a[1]+a[2]*a[2]+a[3]*a[3]
          + c[0]*c[0]+c[1]*c[1]+c[2]*c[2]+c[3]*c[3];
  #pragma unroll
  for (int s2 = 1; s2 < 64; s2 <<= 1) { s += __shfl_xor(s, s2); q += __shfl_xor(q, s2); }
  float mean = s * (1.0f/512.0f);
  float var  = q * (1.0f/512.0f) - mean*mean;
  float rs = rsqrtf(var + 1e-5f);
  fx4 ga = *(const fx4*)(g + l*4);
  fx4 gc = *(const fx4*)(g + 256 + l*4);
  fx4 ba = *(const fx4*)(be + l*4);
  fx4 bc = *(const fx4*)(be + 256 + l*4);
  ushort4 o1, o2;
  o1.x = f2bf((a[0]-mean)*rs*ga[0] + ba[0]);
  o1.y = f2bf((a[1]-mean)*rs*ga[1] + ba[1]);
  o1.z = f2bf((a[2]-mean)*rs*ga[2] + ba[2]);
  o1.w = f2bf((a[3]-mean)*rs*ga[3] + ba[3]);
  o2.x = f2bf((c[0]-mean)*rs*gc[0] + bc[0]);
  o2.y = f2bf((c[1]-mean)*rs*gc[1] + bc[1]);
  o2.z = f2bf((c[2]-mean)*rs*gc[2] + bc[2]);
  o2.w = f2bf((c[3]-mean)*rs*gc[3] + bc[3]);
  *(ushort4*)(O + row*512 + l*4) = o1;
  *(ushort4*)(O + row*512 + 256 + l*4) = o2;
}

// ---------------- GEMM (R6 structure, unchanged) ----------------
template<int MODE, int TN>
__global__ __launch_bounds__(256) void gemm_kernel(
    const unsigned short* __restrict__ A,
    const unsigned short* __restrict__ Bm,
    const float* __restrict__ bias,
    const float* resid,           // no __restrict__: MODE 3 aliases resid == C
    void* C,
    int M, int N, int K) {
  constexpr int MI  = (TN == 128) ? 2 : 1;    // m-fragments per wave
  constexpr int BW  = (TN == 128) ? 32 : 16;  // B rows staged per wave
  constexpr int NBI = (TN == 128) ? 4 : 2;    // B staging insts per wave
  __shared__ unsigned short As[64*64];        // 8 KB
  __shared__ unsigned short Bs[TN*64];        // 16 or 8 KB
  int m0 = blockIdx.y * 64, n0 = blockIdx.x * TN;
  int t = threadIdx.x;
  int w = t >> 6, l = t & 63;
  int wm = (TN == 128) ? (w >> 1) : w;        // wave m index
  int wn = (TN == 128) ? (w & 1) : 0;
  int lid = l & 15, quad = l >> 4;
  int lrow = l >> 3, lch = (l & 7) ^ lrow;    // xor-swizzled source chunk

  const unsigned short* gA = A  + (size_t)(m0 + w*16 + lrow)*K + lch*8;
  const unsigned short* gB = Bm + (size_t)(n0 + w*BW + lrow)*K + lch*8;
  unsigned short* lA0 = As + (w*16    )*64;
  unsigned short* lA1 = As + (w*16 + 8)*64;
  unsigned short* lB[NBI];
  #pragma unroll
  for (int i = 0; i < NBI; i++) lB[i] = Bs + (w*BW + i*8)*64;

  fx4 acc[MI][4];
  #pragma unroll
  for (int i = 0; i < MI; i++)
    #pragma unroll
    for (int j = 0; j < 4; j++) acc[i][j] = (fx4){0.f,0.f,0.f,0.f};

  int xA = (lid & 7) * 8;   // fragment-read xor offset (elements)

  for (int k0 = 0; k0 < K; k0 += 64) {
    load_lds16(gA,       lA0);
    load_lds16(gA + 8*K, lA1);
    #pragma unroll
    for (int i = 0; i < NBI; i++) load_lds16(gB + (size_t)(i*8)*K, lB[i]);
    gA += 64; gB += 64;
    __syncthreads();                 // vmcnt(0) drain + barrier
    #pragma unroll
    for (int s = 0; s < 2; s++) {
      int cbase = (s*4 + quad) * 8;
      bf16x8 af[MI], bf[4];
      #pragma unroll
      for (int i = 0; i < MI; i++) {
        int ra = wm*(MI*16) + i*16 + lid;
        af[i] = *(const bf16x8*)(As + ra*64 + (cbase ^ xA));
      }
      #pragma unroll
      for (int j = 0; j < 4; j++) {
        int rb = wn*64 + j*16 + lid;
        bf[j] = *(const bf16x8*)(Bs + rb*64 + (cbase ^ xA));
      }
      #pragma unroll
      for (int i = 0; i < MI; i++)
        #pragma unroll
        for (int j = 0; j < 4; j++)
          acc[i][j] = __builtin_amdgcn_mfma_f32_16x16x32_bf16(af[i], bf[j], acc[i][j], 0, 0, 0);
    }
    __syncthreads();
  }

  #pragma unroll
  for (int i = 0; i < MI; i++) {
    #pragma unroll
    for (int j = 0; j < 4; j++) {
      int col = n0 + wn*64 + j*16 + lid;
      float bv = bias[col];
      #pragma unroll
      for (int r = 0; r < 4; r++) {
        int row = m0 + wm*(MI*16) + i*16 + quad*4 + r;
        float v = acc[i][j][r] + bv;
        if (MODE == 0) {
          if (col < 512) v *= 0.125f;   // fold HD^-0.5 into Q
          ((unsigned short*)C)[(size_t)row*N + col] = f2bf(v);
        } else if (MODE == 1 || MODE == 3) {
          v += resid[(size_t)row*N + col];
          ((float*)C)[(size_t)row*N + col] = v;
        } else {  // MODE 2: exact GELU
          float gl = 0.5f * v * (1.0f + erff(v * 0.70710678118654752f));
          ((unsigned short*)C)[(size_t)row*N + col] = f2bf(gl);
        }
      }
    }
  }
}

// ---------------- fused attention ----------------
// R7: (a) K staged in 4x128-row chunks -> LDS 24 KB (was 43), 4 blocks/CU resident
//     (wave-capped) to hide V-gather latency (R6 regression was stall-time only);
//     (b) bisection bounds from data: lo = group-min(per-lane max)-1, hi = row max.
//     Proof of exactness: lo < k16 (min lane-max <= k16), hi > k16 (hi=k1), and
//     cnt(>=hi)=1<16; round-up mid => at d==2 mid=lo+1=k16 exits with cnt==16.
//     Initial interval ~2^21 vs 2^32 -> ~8-12 iters vs ~25.
__global__ __launch_bounds__(256) void attn_kernel(
    const unsigned short* __restrict__ QKV,   // [8192][1536] bf16, Q pre-scaled
    const float* __restrict__ rel_emb,        // [1023][8]
    unsigned short* __restrict__ Aout) {      // [8192][512] bf16
  __shared__ float smem[6144];                // 24 KB
  unsigned short* Ks = (unsigned short*)smem; // [128][72] bf16
  float* bias_s = smem + 4608;                // [1023]
  float* pr = smem + 5632;                    // [4 waves][4 groups][16e+16m]
  int blk = blockIdx.x;
  int q0 = (blk & 7) << 6;
  int bh = blk >> 3;
  int b = bh >> 3, h = bh & 7;
  int t = threadIdx.x;
  int w = t >> 6, l = t & 63;
  int lid = l & 15, quad = l >> 4;

  for (int i = t; i < 1023; i += 256) bias_s[i] = rel_emb[i*8 + h];

  int qn = q0 + w*16 + lid;
  const unsigned short* qp = QKV + ((size_t)(b*512 + qn))*1536 + h*64 + quad*8;
  bf16x8 qf0 = *(const bf16x8*)qp;
  bf16x8 qf1 = *(const bf16x8*)(qp + 32);

  fx4 acc[32];
  #pragma unroll
  for (int i = 0; i < 32; i++) acc[i] = (fx4){0.f,0.f,0.f,0.f};

  #pragma unroll 1
  for (int chunk = 0; chunk < 4; chunk++) {
    __syncthreads();
    #pragma unroll
    for (int i = 0; i < 4; i++) {        // stage 128 keys x 64 dims bf16
      int c = t + i*256;
      int row = c >> 3, ch = c & 7;
      uint4 d = *(const uint4*)(QKV + ((size_t)(b*512 + chunk*128 + row))*1536 + 512 + h*64 + ch*8);
      *(uint4*)(Ks + row*72 + ch*8) = d;
    }
    __syncthreads();
    #pragma unroll
    for (int kt = 0; kt < 8; kt++) {
      const unsigned short* kp = Ks + (kt*16 + lid)*72 + quad*8;
      bf16x8 kb0 = *(const bf16x8*)kp;
      bf16x8 kb1 = *(const bf16x8*)(kp + 32);
      int ai = chunk*8 + kt;
      acc[ai] = __builtin_amdgcn_mfma_f32_16x16x32_bf16(qf0, kb0, acc[ai], 0, 0, 0);
      acc[ai] = __builtin_amdgcn_mfma_f32_16x16x32_bf16(qf1, kb1, acc[ai], 0, 0, 0);
    }
  }

  // ---- pack logits+bias into monotonic keys, in place in acc ----
  // key: 23-bit monotonic value | 9-bit complemented index (unique; exact
  // tie-break by lowest index, matching lax.top_k)
  int nb = q0 + w*16 + quad*4;   // first of this group's 4 rows
  #pragma unroll
  for (int kt = 0; kt < 32; kt++) {
    int m = kt*16 + lid;
    int bidx = m - nb + 511;
    #pragma unroll
    for (int r = 0; r < 4; r++) {
      float v = acc[kt][r] + bias_s[bidx - r];
      unsigned mu = __float_as_uint(v);
      mu = (mu & 0x80000000u) ? ~mu : (mu | 0x80000000u);
      acc[kt][r] = __uint_as_float((mu & 0xFFFFFE00u) | (unsigned)(511 - m));
    }
  }

  // ---- data-derived bounds: per-lane max, then group min/max butterfly ----
  unsigned mx0=0, mx1=0, mx2=0, mx3=0;
  #pragma unroll
  for (int kt = 0; kt < 32; kt++) {
    unsigned u0 = __float_as_uint(acc[kt][0]); mx0 = u0 > mx0 ? u0 : mx0;
    unsigned u1 = __float_as_uint(acc[kt][1]); mx1 = u1 > mx1 ? u1 : mx1;
    unsigned u2 = __float_as_uint(acc[kt][2]); mx2 = u2 > mx2 ? u2 : mx2;
    unsigned u3 = __float_as_uint(acc[kt][3]); mx3 = u3 > mx3 ? u3 : mx3;
  }
  unsigned mn0=mx0, mn1=mx1, mn2=mx2, mn3=mx3;
  #pragma unroll
  for (int s2 = 1; s2 < 16; s2 <<= 1) {
    unsigned o;
    o = __shfl_xor(mn0, s2); mn0 = o < mn0 ? o : mn0;
    o = __shfl_xor(mn1, s2); mn1 = o < mn1 ? o : mn1;
    o = __shfl_xor(mn2, s2); mn2 = o < mn2 ? o : mn2;
    o = __shfl_xor(mn3, s2); mn3 = o < mn3 ? o : mn3;
    o = __shfl_xor(mx0, s2); mx0 = o > mx0 ? o : mx0;
    o = __shfl_xor(mx1, s2); mx1 = o > mx1 ? o : mx1;
    o = __shfl_xor(mx2, s2); mx2 = o > mx2 ? o : mx2;
    o = __shfl_xor(mx3, s2); mx3 = o > mx3 ? o : mx3;
  }
  unsigned lo0 = mn0 - (mn0 ? 1u : 0u), hi0 = mx0;
  unsigned lo1 = mn1 - (mn1 ? 1u : 0u), hi1 = mx1;
  unsigned lo2 = mn2 - (mn2 ? 1u : 0u), hi2 = mx2;
  unsigned lo3 = mn3 - (mn3 ? 1u : 0u), hi3 = mx3;

  // ---- combined bisection: 16 rows per wave in parallel ----
  unsigned th0=0, th1=0, th2=0, th3=0;
  unsigned done = 0;
  #pragma unroll 1
  for (int it = 0; it < 34; ++it) {
    unsigned d_;
    d_ = hi0-lo0; unsigned mid0 = lo0 + (d_>>1) + (d_&1u);
    d_ = hi1-lo1; unsigned mid1 = lo1 + (d_>>1) + (d_&1u);
    d_ = hi2-lo2; unsigned mid2 = lo2 + (d_>>1) + (d_&1u);
    d_ = hi3-lo3; unsigned mid3 = lo3 + (d_>>1) + (d_&1u);
    unsigned c0=0, c1=0, c2=0, c3=0;
    #pragma unroll
    for (int kt = 0; kt < 32; kt++) {
      c0 += (__float_as_uint(acc[kt][0]) >= mid0);
      c1 += (__float_as_uint(acc[kt][1]) >= mid1);
      c2 += (__float_as_uint(acc[kt][2]) >= mid2);
      c3 += (__float_as_uint(acc[kt][3]) >= mid3);
    }
    unsigned p01 = c0 | (c1 << 16);
    unsigned p23 = c2 | (c3 << 16);
    #pragma unroll
    for (int s2 = 1; s2 < 16; s2 <<= 1) {   // in-group butterfly
      p01 += __shfl_xor(p01, s2);
      p23 += __shfl_xor(p23, s2);
    }
    unsigned C0 = p01 & 0xFFFFu, C1 = p01 >> 16;
    unsigned C2 = p23 & 0xFFFFu, C3 = p23 >> 16;
    { bool f = !(done & 1u); bool e = f && (C0 == 16u);
      th0 = e ? mid0 : th0; done |= e ? 1u : 0u;
      lo0 = (f && C0 > 16u) ? mid0 : lo0; hi0 = (f && C0 < 16u) ? mid0 : hi0; }
    { bool f = !(done & 2u); bool e = f && (C1 == 16u);
      th1 = e ? mid1 : th1; done |= e ? 2u : 0u;
      lo1 = (f && C1 > 16u) ? mid1 : lo1; hi1 = (f && C1 < 16u) ? mid1 : hi1; }
    { bool f = !(done & 4u); bool e = f && (C2 == 16u);
      th2 = e ? mid2 : th2; done |= e ? 4u : 0u;
      lo2 = (f && C2 > 16u) ? mid2 : lo2; hi2 = (f && C2 < 16u) ? mid2 : hi2; }
    { bool f = !(done & 8u); bool e = f && (C3 == 16u);
      th3 = e ? mid3 : th3; done |= e ? 8u : 0u;
      lo3 = (f && C3 > 16u) ? mid3 : lo3; hi3 = (f && C3 < 16u) ? mid3 : hi3; }
    if (__all((int)(done == 15u))) break;
  }

  // ---- per-row compaction (ballot-prefix, deterministic) + sparse PV ----
  float* prE = pr + w*128 + quad*32;
  int*   prM = (int*)prE + 16;
  unsigned below = (1u << lid) - 1u;
  #pragma unroll
  for (int r = 0; r < 4; r++) {
    unsigned thr = (r==0) ? th0 : (r==1) ? th1 : (r==2) ? th2 : th3;
    int base = 0;
    #pragma unroll
    for (int kt = 0; kt < 32; kt++) {
      unsigned u = __float_as_uint(acc[kt][r]);
      bool sel = u >= thr;
      unsigned long long bm = __ballot(sel);
      unsigned gm = (unsigned)(bm >> (quad*16)) & 0xFFFFu;
      if (sel) {
        int slot = base + __popc(gm & below);
        unsigned vu = u & 0xFFFFFE00u;
        vu = (vu & 0x80000000u) ? (vu & 0x7FFFFFFFu) : ~vu;
        float e = exp2f(__uint_as_float(vu) * 1.44269504f);
        if (slot < 16) { prE[slot] = e; prM[slot] = 511 - (int)(u & 0x1FFu); }
      }
      base += __popc(gm);
    }
    __threadfence_block();
    int n = nb + r;
    float o0=0.f, o1=0.f, o2=0.f, o3=0.f, es=0.f;
    #pragma unroll
    for (int k2 = 0; k2 < 16; k2++) {
      float e = prE[k2];
      int m = prM[k2];
      const unsigned short* vp = QKV + ((size_t)(b*512 + m))*1536 + 1024 + h*64 + lid*4;
      ushort4 v4 = *(const ushort4*)vp;
      es += e;
      o0 += e * bf2f(v4.x); o1 += e * bf2f(v4.y);
      o2 += e * bf2f(v4.z); o3 += e * bf2f(v4.w);
    }
    float inv = 1.0f / es;
    ushort4 ov;
    ov.x = f2bf(o0*inv); ov.y = f2bf(o1*inv);
    ov.z = f2bf(o2*inv); ov.w = f2bf(o3*inv);
    *(ushort4*)(Aout + ((size_t)(b*512 + n))*512 + h*64 + lid*4) = ov;
    __threadfence_block();   // pr reused next r
  }
}

// ---------------- host ----------------
// ws budget (lifetime-aliased, ~46 MB — R1 overflow corrupted pristine inputs):
//   R1 (8 MB):  xn1 -> aout -> xn2
//   R2 (32 MB): qkvb (24 MB) -> hbuf
//   x2 lives in d_out (gemm1 writes, ln2 reads, gemm3 same-addr RMW per element)
extern "C" void kernel_launch(void* const* d_in, const int* in_sizes, int n_in,
                              void* d_out, int out_size, void* d_ws, size_t ws_size,
                              hipStream_t stream) {
  const float* x   = (const float*)d_in[0];
  const float* wq  = (const float*)d_in[1];
  const float* bq  = (const float*)d_in[2];
  const float* wk  = (const float*)d_in[3];
  const float* bk  = (const float*)d_in[4];
  const float* wv  = (const float*)d_in[5];
  const float* bv  = (const float*)d_in[6];
  const float* wo  = (const float*)d_in[7];
  const float* bo  = (const float*)d_in[8];
  const float* g1  = (const float*)d_in[9];
  const float* be1 = (const float*)d_in[10];
  const float* g2  = (const float*)d_in[11];
  const float* be2 = (const float*)d_in[12];
  const float* w1  = (const float*)d_in[13];
  const float* bf1 = (const float*)d_in[14];
  const float* w2  = (const float*)d_in[15];
  const float* bf2 = (const float*)d_in[16];
  const float* rel = (const float*)d_in[17];

  char* p = (char*)d_ws;
  size_t off = 0;
  auto alloc = [&](size_t bytes) {
    size_t cur = off;
    off += (bytes + 255) & ~(size_t)255;
    return (void*)(p + cur);
  };
  unsigned short* wqkvT = (unsigned short*)alloc((size_t)1536*512*2);
  unsigned short* woT   = (unsigned short*)alloc((size_t)512*512*2);
  unsigned short* w1T   = (unsigned short*)alloc((size_t)2048*512*2);
  unsigned short* w2T   = (unsigned short*)alloc((size_t)512*2048*2);
  float*          bqkv  = (float*)alloc(1536*4);
  unsigned short* R1    = (unsigned short*)alloc((size_t)MM*512*2);   // 8MB
  unsigned short* R2    = (unsigned short*)alloc((size_t)MM*2048*2);  // 32MB

  unsigned short* xn1  = R1;                    // ln1 -> gemm0
  unsigned short* aout = R1;                    // attn -> gemm1 (xn1 dead)
  unsigned short* xn2  = R1;                    // ln2 -> gemm2 (aout dead)
  unsigned short* qkvb = R2;                    // gemm0 -> attn (24MB of 32)
  unsigned short* hbuf = R2;                    // gemm2 -> gemm3 (qkvb dead)
  float*          x2   = (float*)d_out;         // gemm1 -> ln2/gemm3
  (void)ws_size; (void)in_sizes; (void)n_in; (void)out_size;

  transpose_all<<<3072, dim3(32, 8), 0, stream>>>(wq, wk, wv, wo, w1, w2,
                                                  wqkvT, woT, w1T, w2T);
  concat_bias<<<6, 256, 0, stream>>>(bq, bk, bv, bqkv);

  ln_kernel<<<2048, 256, 0, stream>>>(x, g1, be1, xn1);
  gemm_kernel<0,128><<<dim3(12, 128), 256, 0, stream>>>(xn1, wqkvT, bqkv, nullptr, qkvb, MM, 1536, 512);
  attn_kernel<<<1024, 256, 0, stream>>>(qkvb, rel, aout);
  gemm_kernel<1,64><<<dim3(8, 128), 256, 0, stream>>>(aout, woT, bo, x, x2, MM, 512, 512);
  ln_kernel<<<2048, 256, 0, stream>>>(x2, g2, be2, xn2);
  gemm_kernel<2,128><<<dim3(16, 128), 256, 0, stream>>>(xn2, w1T, bf1, nullptr, hbuf, MM, 2048, 512);
  gemm_kernel<3,64><<<dim3(8, 128), 256, 0, stream>>>(hbuf, w2T, bf2, x2, (float*)d_out, MM, 512, 2048);
}

// Round 8
// 347.335 us; speedup vs baseline: 1.3340x; 1.3340x over previous
//
#include <hip/hip_runtime.h>
#include <hip/hip_bf16.h>

// B=16, N=512, D=512, H=8, HD=64, K(topk)=16, MSL=512
#define BB 16
#define NN 512
#define DD 512
#define HH 8
#define HD 64
#define MM (BB*NN)      // 8192 rows
#define DFF 2048

typedef __attribute__((ext_vector_type(8))) short bf16x8;
typedef __attribute__((ext_vector_type(4))) float fx4;

static __device__ __forceinline__ unsigned short f2bf(float f) {
  unsigned u = __float_as_uint(f);
  u += 0x7FFFu + ((u >> 16) & 1u);   // RNE
  return (unsigned short)(u >> 16);
}
static __device__ __forceinline__ float bf2f(unsigned short s) {
  return __uint_as_float(((unsigned)s) << 16);
}

// async global->LDS DMA, 16B/lane, dest = wave-uniform base + lane*16
static __device__ __forceinline__ void load_lds16(const unsigned short* g, unsigned short* l) {
  __builtin_amdgcn_global_load_lds(
      (const __attribute__((address_space(1))) void*)g,
      (__attribute__((address_space(3))) void*)l, 16, 0, 0);
}

// ---------------- fused weight transpose: 6 matrices [K][N] fp32 -> [N][K] bf16 ----------------
__global__ void transpose_all(const float* __restrict__ wq, const float* __restrict__ wk,
                              const float* __restrict__ wv, const float* __restrict__ wo,
                              const float* __restrict__ w1, const float* __restrict__ w2,
                              unsigned short* __restrict__ wqkvT, unsigned short* __restrict__ woT,
                              unsigned short* __restrict__ w1T, unsigned short* __restrict__ w2T) {
  __shared__ float tl[32][33];
  int id = blockIdx.x;
  const float* src; unsigned short* dst; int K, N, bx, by;
  if (id < 1024) {
    int m = id >> 8, tt = id & 255;
    src = (m == 0) ? wq : (m == 1) ? wk : (m == 2) ? wv : wo;
    dst = (m == 3) ? woT : wqkvT + m * 512 * 512;
    K = 512; N = 512; bx = tt & 15; by = tt >> 4;
  } else if (id < 2048) {
    int tt = id - 1024;
    src = w1; dst = w1T; K = 512; N = 2048; bx = tt & 63; by = tt >> 6;
  } else {
    int tt = id - 2048;
    src = w2; dst = w2T; K = 2048; N = 512; bx = tt & 15; by = tt >> 4;
  }
  int tx = threadIdx.x, ty = threadIdx.y;        // (32,8)
  int x0 = bx * 32, y0 = by * 32;
  #pragma unroll
  for (int i = 0; i < 4; i++)
    tl[ty + i*8][tx] = src[(size_t)(y0 + ty + i*8) * N + x0 + tx];
  __syncthreads();
  #pragma unroll
  for (int i = 0; i < 4; i++)
    dst[(size_t)(x0 + ty + i*8) * K + y0 + tx] = f2bf(tl[tx][ty + i*8]);
}

__global__ void concat_bias(const float* __restrict__ bq, const float* __restrict__ bk,
                            const float* __restrict__ bv, float* __restrict__ o) {
  int t = blockIdx.x * 256 + threadIdx.x;
  if (t < 512) o[t] = bq[t];
  else if (t < 1024) o[t] = bk[t - 512];
  else if (t < 1536) o[t] = bv[t - 1024];
}

// ---------------- LayerNorm: fp32 [rows][512] -> bf16 ----------------
__global__ __launch_bounds__(256) void ln_kernel(const float* __restrict__ X,
                                                 const float* __restrict__ g,
                                                 const float* __restrict__ be,
                                                 unsigned short* __restrict__ O) {
  int w = threadIdx.x >> 6, l = threadIdx.x & 63;
  size_t row = (size_t)blockIdx.x * 4 + w;
  const float* xr = X + row * 512;
  fx4 a = *(const fx4*)(xr + l*4);
  fx4 c = *(const fx4*)(xr + 256 + l*4);
  float s = a[0]+a[1]+a[2]+a[3] + c[0]+c[1]+c[2]+c[3];
  float q = a[0]*a[0]+a[1]*a[1]+a[2]*a[2]+a[3]*a[3]
          + c[0]*c[0]+c[1]*c[1]+c[2]*c[2]+c[3]*c[3];
  #pragma unroll
  for (int s2 = 1; s2 < 64; s2 <<= 1) { s += __shfl_xor(s, s2); q += __shfl_xor(q, s2); }
  float mean = s * (1.0f/512.0f);
  float var  = q * (1.0f/512.0f) - mean*mean;
  float rs = rsqrtf(var + 1e-5f);
  fx4 ga = *(const fx4*)(g + l*4);
  fx4 gc = *(const fx4*)(g + 256 + l*4);
  fx4 ba = *(const fx4*)(be + l*4);
  fx4 bc = *(const fx4*)(be + 256 + l*4);
  ushort4 o1, o2;
  o1.x = f2bf((a[0]-mean)*rs*ga[0] + ba[0]);
  o1.y = f2bf((a[1]-mean)*rs*ga[1] + ba[1]);
  o1.z = f2bf((a[2]-mean)*rs*ga[2] + ba[2]);
  o1.w = f2bf((a[3]-mean)*rs*ga[3] + ba[3]);
  o2.x = f2bf((c[0]-mean)*rs*gc[0] + bc[0]);
  o2.y = f2bf((c[1]-mean)*rs*gc[1] + bc[1]);
  o2.z = f2bf((c[2]-mean)*rs*gc[2] + bc[2]);
  o2.w = f2bf((c[3]-mean)*rs*gc[3] + bc[3]);
  *(ushort4*)(O + row*512 + l*4) = o1;
  *(ushort4*)(O + row*512 + 256 + l*4) = o2;
}

// ---------------- GEMM (R6 structure, unchanged) ----------------
template<int MODE, int TN>
__global__ __launch_bounds__(256) void gemm_kernel(
    const unsigned short* __restrict__ A,
    const unsigned short* __restrict__ Bm,
    const float* __restrict__ bias,
    const float* resid,           // no __restrict__: MODE 3 aliases resid == C
    void* C,
    int M, int N, int K) {
  constexpr int MI  = (TN == 128) ? 2 : 1;    // m-fragments per wave
  constexpr int BW  = (TN == 128) ? 32 : 16;  // B rows staged per wave
  constexpr int NBI = (TN == 128) ? 4 : 2;    // B staging insts per wave
  __shared__ unsigned short As[64*64];        // 8 KB
  __shared__ unsigned short Bs[TN*64];        // 16 or 8 KB
  int m0 = blockIdx.y * 64, n0 = blockIdx.x * TN;
  int t = threadIdx.x;
  int w = t >> 6, l = t & 63;
  int wm = (TN == 128) ? (w >> 1) : w;        // wave m index
  int wn = (TN == 128) ? (w & 1) : 0;
  int lid = l & 15, quad = l >> 4;
  int lrow = l >> 3, lch = (l & 7) ^ lrow;    // xor-swizzled source chunk

  const unsigned short* gA = A  + (size_t)(m0 + w*16 + lrow)*K + lch*8;
  const unsigned short* gB = Bm + (size_t)(n0 + w*BW + lrow)*K + lch*8;
  unsigned short* lA0 = As + (w*16    )*64;
  unsigned short* lA1 = As + (w*16 + 8)*64;
  unsigned short* lB[NBI];
  #pragma unroll
  for (int i = 0; i < NBI; i++) lB[i] = Bs + (w*BW + i*8)*64;

  fx4 acc[MI][4];
  #pragma unroll
  for (int i = 0; i < MI; i++)
    #pragma unroll
    for (int j = 0; j < 4; j++) acc[i][j] = (fx4){0.f,0.f,0.f,0.f};

  int xA = (lid & 7) * 8;   // fragment-read xor offset (elements)

  for (int k0 = 0; k0 < K; k0 += 64) {
    load_lds16(gA,       lA0);
    load_lds16(gA + 8*K, lA1);
    #pragma unroll
    for (int i = 0; i < NBI; i++) load_lds16(gB + (size_t)(i*8)*K, lB[i]);
    gA += 64; gB += 64;
    __syncthreads();                 // vmcnt(0) drain + barrier
    #pragma unroll
    for (int s = 0; s < 2; s++) {
      int cbase = (s*4 + quad) * 8;
      bf16x8 af[MI], bf[4];
      #pragma unroll
      for (int i = 0; i < MI; i++) {
        int ra = wm*(MI*16) + i*16 + lid;
        af[i] = *(const bf16x8*)(As + ra*64 + (cbase ^ xA));
      }
      #pragma unroll
      for (int j = 0; j < 4; j++) {
        int rb = wn*64 + j*16 + lid;
        bf[j] = *(const bf16x8*)(Bs + rb*64 + (cbase ^ xA));
      }
      #pragma unroll
      for (int i = 0; i < MI; i++)
        #pragma unroll
        for (int j = 0; j < 4; j++)
          acc[i][j] = __builtin_amdgcn_mfma_f32_16x16x32_bf16(af[i], bf[j], acc[i][j], 0, 0, 0);
    }
    __syncthreads();
  }

  #pragma unroll
  for (int i = 0; i < MI; i++) {
    #pragma unroll
    for (int j = 0; j < 4; j++) {
      int col = n0 + wn*64 + j*16 + lid;
      float bv = bias[col];
      #pragma unroll
      for (int r = 0; r < 4; r++) {
        int row = m0 + wm*(MI*16) + i*16 + quad*4 + r;
        float v = acc[i][j][r] + bv;
        if (MODE == 0) {
          if (col < 512) v *= 0.125f;   // fold HD^-0.5 into Q
          ((unsigned short*)C)[(size_t)row*N + col] = f2bf(v);
        } else if (MODE == 1 || MODE == 3) {
          v += resid[(size_t)row*N + col];
          ((float*)C)[(size_t)row*N + col] = v;
        } else {  // MODE 2: exact GELU
          float gl = 0.5f * v * (1.0f + erff(v * 0.70710678118654752f));
          ((unsigned short*)C)[(size_t)row*N + col] = f2bf(gl);
        }
      }
    }
  }
}

// ---------------- fused attention ----------------
// R8: R7's chunk loop was `#pragma unroll 1` with acc[chunk*8+kt] -> runtime
//     index into acc[32] -> compiler spilled the whole accumulator to scratch
//     (WRITE_SIZE 8->397 MB). FULLY UNROLL so all acc indices are constants.
//     Keeps R7's wins: 24 KB LDS (4 blocks/CU), data-derived bisection bounds
//     (lo = group-min(lane max)-1 < k16, hi = row max; round-up mid => exact).
__global__ __launch_bounds__(256) void attn_kernel(
    const unsigned short* __restrict__ QKV,   // [8192][1536] bf16, Q pre-scaled
    const float* __restrict__ rel_emb,        // [1023][8]
    unsigned short* __restrict__ Aout) {      // [8192][512] bf16
  __shared__ float smem[6144];                // 24 KB
  unsigned short* Ks = (unsigned short*)smem; // [128][72] bf16
  float* bias_s = smem + 4608;                // [1023]
  float* pr = smem + 5632;                    // [4 waves][4 groups][16e+16m]
  int blk = blockIdx.x;
  int q0 = (blk & 7) << 6;
  int bh = blk >> 3;
  int b = bh >> 3, h = bh & 7;
  int t = threadIdx.x;
  int w = t >> 6, l = t & 63;
  int lid = l & 15, quad = l >> 4;

  for (int i = t; i < 1023; i += 256) bias_s[i] = rel_emb[i*8 + h];

  int qn = q0 + w*16 + lid;
  const unsigned short* qp = QKV + ((size_t)(b*512 + qn))*1536 + h*64 + quad*8;
  bf16x8 qf0 = *(const bf16x8*)qp;
  bf16x8 qf1 = *(const bf16x8*)(qp + 32);

  fx4 acc[32];
  #pragma unroll
  for (int i = 0; i < 32; i++) acc[i] = (fx4){0.f,0.f,0.f,0.f};

  #pragma unroll
  for (int chunk = 0; chunk < 4; chunk++) {   // FULLY UNROLLED (R8 fix)
    __syncthreads();
    #pragma unroll
    for (int i = 0; i < 4; i++) {        // stage 128 keys x 64 dims bf16
      int c = t + i*256;
      int row = c >> 3, ch = c & 7;
      uint4 d = *(const uint4*)(QKV + ((size_t)(b*512 + chunk*128 + row))*1536 + 512 + h*64 + ch*8);
      *(uint4*)(Ks + row*72 + ch*8) = d;
    }
    __syncthreads();
    #pragma unroll
    for (int kt = 0; kt < 8; kt++) {
      const unsigned short* kp = Ks + (kt*16 + lid)*72 + quad*8;
      bf16x8 kb0 = *(const bf16x8*)kp;
      bf16x8 kb1 = *(const bf16x8*)(kp + 32);
      int ai = chunk*8 + kt;
      acc[ai] = __builtin_amdgcn_mfma_f32_16x16x32_bf16(qf0, kb0, acc[ai], 0, 0, 0);
      acc[ai] = __builtin_amdgcn_mfma_f32_16x16x32_bf16(qf1, kb1, acc[ai], 0, 0, 0);
    }
  }

  // ---- pack logits+bias into monotonic keys, in place in acc ----
  int nb = q0 + w*16 + quad*4;   // first of this group's 4 rows
  #pragma unroll
  for (int kt = 0; kt < 32; kt++) {
    int m = kt*16 + lid;
    int bidx = m - nb + 511;
    #pragma unroll
    for (int r = 0; r < 4; r++) {
      float v = acc[kt][r] + bias_s[bidx - r];
      unsigned mu = __float_as_uint(v);
      mu = (mu & 0x80000000u) ? ~mu : (mu | 0x80000000u);
      acc[kt][r] = __uint_as_float((mu & 0xFFFFFE00u) | (unsigned)(511 - m));
    }
  }

  // ---- data-derived bounds: per-lane max, then group min/max butterfly ----
  unsigned mx0=0, mx1=0, mx2=0, mx3=0;
  #pragma unroll
  for (int kt = 0; kt < 32; kt++) {
    unsigned u0 = __float_as_uint(acc[kt][0]); mx0 = u0 > mx0 ? u0 : mx0;
    unsigned u1 = __float_as_uint(acc[kt][1]); mx1 = u1 > mx1 ? u1 : mx1;
    unsigned u2 = __float_as_uint(acc[kt][2]); mx2 = u2 > mx2 ? u2 : mx2;
    unsigned u3 = __float_as_uint(acc[kt][3]); mx3 = u3 > mx3 ? u3 : mx3;
  }
  unsigned mn0=mx0, mn1=mx1, mn2=mx2, mn3=mx3;
  #pragma unroll
  for (int s2 = 1; s2 < 16; s2 <<= 1) {
    unsigned o;
    o = __shfl_xor(mn0, s2); mn0 = o < mn0 ? o : mn0;
    o = __shfl_xor(mn1, s2); mn1 = o < mn1 ? o : mn1;
    o = __shfl_xor(mn2, s2); mn2 = o < mn2 ? o : mn2;
    o = __shfl_xor(mn3, s2); mn3 = o < mn3 ? o : mn3;
    o = __shfl_xor(mx0, s2); mx0 = o > mx0 ? o : mx0;
    o = __shfl_xor(mx1, s2); mx1 = o > mx1 ? o : mx1;
    o = __shfl_xor(mx2, s2); mx2 = o > mx2 ? o : mx2;
    o = __shfl_xor(mx3, s2); mx3 = o > mx3 ? o : mx3;
  }
  unsigned lo0 = mn0 - (mn0 ? 1u : 0u), hi0 = mx0;
  unsigned lo1 = mn1 - (mn1 ? 1u : 0u), hi1 = mx1;
  unsigned lo2 = mn2 - (mn2 ? 1u : 0u), hi2 = mx2;
  unsigned lo3 = mn3 - (mn3 ? 1u : 0u), hi3 = mx3;

  // ---- combined bisection: 16 rows per wave in parallel ----
  unsigned th0=0, th1=0, th2=0, th3=0;
  unsigned done = 0;
  #pragma unroll 1
  for (int it = 0; it < 34; ++it) {
    unsigned d_;
    d_ = hi0-lo0; unsigned mid0 = lo0 + (d_>>1) + (d_&1u);
    d_ = hi1-lo1; unsigned mid1 = lo1 + (d_>>1) + (d_&1u);
    d_ = hi2-lo2; unsigned mid2 = lo2 + (d_>>1) + (d_&1u);
    d_ = hi3-lo3; unsigned mid3 = lo3 + (d_>>1) + (d_&1u);
    unsigned c0=0, c1=0, c2=0, c3=0;
    #pragma unroll
    for (int kt = 0; kt < 32; kt++) {
      c0 += (__float_as_uint(acc[kt][0]) >= mid0);
      c1 += (__float_as_uint(acc[kt][1]) >= mid1);
      c2 += (__float_as_uint(acc[kt][2]) >= mid2);
      c3 += (__float_as_uint(acc[kt][3]) >= mid3);
    }
    unsigned p01 = c0 | (c1 << 16);
    unsigned p23 = c2 | (c3 << 16);
    #pragma unroll
    for (int s2 = 1; s2 < 16; s2 <<= 1) {   // in-group butterfly
      p01 += __shfl_xor(p01, s2);
      p23 += __shfl_xor(p23, s2);
    }
    unsigned C0 = p01 & 0xFFFFu, C1 = p01 >> 16;
    unsigned C2 = p23 & 0xFFFFu, C3 = p23 >> 16;
    { bool f = !(done & 1u); bool e = f && (C0 == 16u);
      th0 = e ? mid0 : th0; done |= e ? 1u : 0u;
      lo0 = (f && C0 > 16u) ? mid0 : lo0; hi0 = (f && C0 < 16u) ? mid0 : hi0; }
    { bool f = !(done & 2u); bool e = f && (C1 == 16u);
      th1 = e ? mid1 : th1; done |= e ? 2u : 0u;
      lo1 = (f && C1 > 16u) ? mid1 : lo1; hi1 = (f && C1 < 16u) ? mid1 : hi1; }
    { bool f = !(done & 4u); bool e = f && (C2 == 16u);
      th2 = e ? mid2 : th2; done |= e ? 4u : 0u;
      lo2 = (f && C2 > 16u) ? mid2 : lo2; hi2 = (f && C2 < 16u) ? mid2 : hi2; }
    { bool f = !(done & 8u); bool e = f && (C3 == 16u);
      th3 = e ? mid3 : th3; done |= e ? 8u : 0u;
      lo3 = (f && C3 > 16u) ? mid3 : lo3; hi3 = (f && C3 < 16u) ? mid3 : hi3; }
    if (__all((int)(done == 15u))) break;
  }

  // ---- per-row compaction (ballot-prefix, deterministic) + sparse PV ----
  float* prE = pr + w*128 + quad*32;
  int*   prM = (int*)prE + 16;
  unsigned below = (1u << lid) - 1u;
  #pragma unroll
  for (int r = 0; r < 4; r++) {
    unsigned thr = (r==0) ? th0 : (r==1) ? th1 : (r==2) ? th2 : th3;
    int base = 0;
    #pragma unroll
    for (int kt = 0; kt < 32; kt++) {
      unsigned u = __float_as_uint(acc[kt][r]);
      bool sel = u >= thr;
      unsigned long long bm = __ballot(sel);
      unsigned gm = (unsigned)(bm >> (quad*16)) & 0xFFFFu;
      if (sel) {
        int slot = base + __popc(gm & below);
        unsigned vu = u & 0xFFFFFE00u;
        vu = (vu & 0x80000000u) ? (vu & 0x7FFFFFFFu) : ~vu;
        float e = exp2f(__uint_as_float(vu) * 1.44269504f);
        if (slot < 16) { prE[slot] = e; prM[slot] = 511 - (int)(u & 0x1FFu); }
      }
      base += __popc(gm);
    }
    __threadfence_block();
    int n = nb + r;
    float o0=0.f, o1=0.f, o2=0.f, o3=0.f, es=0.f;
    #pragma unroll
    for (int k2 = 0; k2 < 16; k2++) {
      float e = prE[k2];
      int m = prM[k2];
      const unsigned short* vp = QKV + ((size_t)(b*512 + m))*1536 + 1024 + h*64 + lid*4;
      ushort4 v4 = *(const ushort4*)vp;
      es += e;
      o0 += e * bf2f(v4.x); o1 += e * bf2f(v4.y);
      o2 += e * bf2f(v4.z); o3 += e * bf2f(v4.w);
    }
    float inv = 1.0f / es;
    ushort4 ov;
    ov.x = f2bf(o0*inv); ov.y = f2bf(o1*inv);
    ov.z = f2bf(o2*inv); ov.w = f2bf(o3*inv);
    *(ushort4*)(Aout + ((size_t)(b*512 + n))*512 + h*64 + lid*4) = ov;
    __threadfence_block();   // pr reused next r
  }
}

// ---------------- host ----------------
// ws budget (lifetime-aliased, ~46 MB — R1 overflow corrupted pristine inputs):
//   R1 (8 MB):  xn1 -> aout -> xn2
//   R2 (32 MB): qkvb (24 MB) -> hbuf
//   x2 lives in d_out (gemm1 writes, ln2 reads, gemm3 same-addr RMW per element)
extern "C" void kernel_launch(void* const* d_in, const int* in_sizes, int n_in,
                              void* d_out, int out_size, void* d_ws, size_t ws_size,
                              hipStream_t stream) {
  const float* x   = (const float*)d_in[0];
  const float* wq  = (const float*)d_in[1];
  const float* bq  = (const float*)d_in[2];
  const float* wk  = (const float*)d_in[3];
  const float* bk  = (const float*)d_in[4];
  const float* wv  = (const float*)d_in[5];
  const float* bv  = (const float*)d_in[6];
  const float* wo  = (const float*)d_in[7];
  const float* bo  = (const float*)d_in[8];
  const float* g1  = (const float*)d_in[9];
  const float* be1 = (const float*)d_in[10];
  const float* g2  = (const float*)d_in[11];
  const float* be2 = (const float*)d_in[12];
  const float* w1  = (const float*)d_in[13];
  const float* bf1 = (const float*)d_in[14];
  const float* w2  = (const float*)d_in[15];
  const float* bf2 = (const float*)d_in[16];
  const float* rel = (const float*)d_in[17];

  char* p = (char*)d_ws;
  size_t off = 0;
  auto alloc = [&](size_t bytes) {
    size_t cur = off;
    off += (bytes + 255) & ~(size_t)255;
    return (void*)(p + cur);
  };
  unsigned short* wqkvT = (unsigned short*)alloc((size_t)1536*512*2);
  unsigned short* woT   = (unsigned short*)alloc((size_t)512*512*2);
  unsigned short* w1T   = (unsigned short*)alloc((size_t)2048*512*2);
  unsigned short* w2T   = (unsigned short*)alloc((size_t)512*2048*2);
  float*          bqkv  = (float*)alloc(1536*4);
  unsigned short* R1    = (unsigned short*)alloc((size_t)MM*512*2);   // 8MB
  unsigned short* R2    = (unsigned short*)alloc((size_t)MM*2048*2);  // 32MB

  unsigned short* xn1  = R1;                    // ln1 -> gemm0
  unsigned short* aout = R1;                    // attn -> gemm1 (xn1 dead)
  unsigned short* xn2  = R1;                    // ln2 -> gemm2 (aout dead)
  unsigned short* qkvb = R2;                    // gemm0 -> attn (24MB of 32)
  unsigned short* hbuf = R2;                    // gemm2 -> gemm3 (qkvb dead)
  float*          x2   = (float*)d_out;         // gemm1 -> ln2/gemm3
  (void)ws_size; (void)in_sizes; (void)n_in; (void)out_size;

  transpose_all<<<3072, dim3(32, 8), 0, stream>>>(wq, wk, wv, wo, w1, w2,
                                                  wqkvT, woT, w1T, w2T);
  concat_bias<<<6, 256, 0, stream>>>(bq, bk, bv, bqkv);

  ln_kernel<<<2048, 256, 0, stream>>>(x, g1, be1, xn1);
  gemm_kernel<0,128><<<dim3(12, 128), 256, 0, stream>>>(xn1, wqkvT, bqkv, nullptr, qkvb, MM, 1536, 512);
  attn_kernel<<<1024, 256, 0, stream>>>(qkvb, rel, aout);
  gemm_kernel<1,64><<<dim3(8, 128), 256, 0, stream>>>(aout, woT, bo, x, x2, MM, 512, 512);
  ln_kernel<<<2048, 256, 0, stream>>>(x2, g2, be2, xn2);
  gemm_kernel<2,128><<<dim3(16, 128), 256, 0, stream>>>(xn2, w1T, bf1, nullptr, hbuf, MM, 2048, 512);
  gemm_kernel<3,64><<<dim3(8, 128), 256, 0, stream>>>(hbuf, w2T, bf2, x2, (float*)d_out, MM, 512, 2048);
}